// Round 2
// baseline (5330.453 us; speedup 1.0000x reference)
//
#include <hip/hip_runtime.h>

typedef unsigned short u16;
typedef unsigned int u32;
typedef short s16x8 __attribute__((ext_vector_type(8)));
typedef float f32x4 __attribute__((ext_vector_type(4)));
typedef __bf16 bf16x2 __attribute__((ext_vector_type(2)));

#define BTH 2097152  // 16*512*256

__device__ __forceinline__ u16 f2bf(float f) {
  u32 u = __float_as_uint(f);
  u32 r = (u + 0x7FFFu + ((u >> 16) & 1u)) >> 16;  // RNE
  return (u16)r;
}
__device__ __forceinline__ float bf2f(u16 u) {
  return __uint_as_float(((u32)u) << 16);
}
__device__ __forceinline__ float sigm_(float x) { return 1.f / (1.f + __expf(-x)); }
__device__ __forceinline__ float tanh_(float x) {
  x = fminf(15.f, fmaxf(-15.f, x));
  float e = __expf(2.f * x);
  return (e - 1.f) / (e + 1.f);
}

#if defined(__has_builtin)
#if __has_builtin(__builtin_amdgcn_fdot2_f32_bf16)
#define HAVE_BF16_DOT2 1
#endif
#endif

// acc += dot(bf16x2(a), bf16x2(b))
__device__ __forceinline__ float dotp(u32 a, u32 b, float acc) {
#ifdef HAVE_BF16_DOT2
  return __builtin_amdgcn_fdot2_f32_bf16(__builtin_bit_cast(bf16x2, a),
                                         __builtin_bit_cast(bf16x2, b), acc, false);
#else
  acc += bf2f((u16)(a & 0xFFFFu)) * bf2f((u16)(b & 0xFFFFu));
  acc += bf2f((u16)(a >> 16)) * bf2f((u16)(b >> 16));
  return acc;
#endif
}

__device__ __forceinline__ void async_cp16(const u16* g, u16* l) {
  __builtin_amdgcn_global_load_lds(
      (const __attribute__((address_space(1))) void*)g,
      (__attribute__((address_space(3))) void*)l, 16, 0, 0);
}

// x [b][t][d] f32 -> xb [(t*16+b)][d] bf16
__global__ void cast_x_kernel(const float* __restrict__ x, u16* __restrict__ xb) {
  int e = blockIdx.x * 256 + threadIdx.x;  // < 2097152
  int d = e & 255;
  int r = e >> 8;  // b*512 + t
  int bb = r >> 9, t = r & 511;
  xb[(size_t)((t << 4) | bb) * 256 + d] = f2bf(x[e]);
}

__global__ void cast_w_kernel(const float* __restrict__ w, u16* __restrict__ o, int n) {
  int e = blockIdx.x * 256 + threadIdx.x;
  if (e < n) o[e] = f2bf(w[e]);
}

// B_w [o][d][h] f32 -> Btt [(o*256+h)][d] bf16  (n-major for GEMM B-operand)
__global__ void transpose_b_kernel(const float* __restrict__ Bw, u16* __restrict__ Btt) {
  __shared__ float T[64][65];
  const int o = blockIdx.y;
  const int d0 = (blockIdx.x >> 2) * 64;
  const int h0 = (blockIdx.x & 3) * 64;
  const int tid = threadIdx.x;
  const float* src = Bw + (size_t)o * 65536;
#pragma unroll
  for (int k = 0; k < 16; ++k) {
    int idx = tid + k * 256;
    int rr = idx >> 6, cc = idx & 63;
    T[rr][cc] = src[(size_t)(d0 + rr) * 256 + h0 + cc];
  }
  __syncthreads();
#pragma unroll
  for (int k = 0; k < 16; ++k) {
    int idx = tid + k * 256;
    int rr = idx >> 6, cc = idx & 63;
    Btt[(size_t)(o * 256 + h0 + rr) * 256 + d0 + cc] = f2bf(T[cc][rr]);
  }
}

// C[m][n] = A[m][:] . Bm[n][:]   (A,Bm bf16 row-major over K=256; fp32 accum)
// m97-style: global_load_lds width=16 staging into UNPADDED LDS (lane-order
// contiguity required by the wave-uniform-base+lane*16 LDS dest rule).
template <bool OF32>
__global__ __launch_bounds__(256) void gemm_nt(
    const u16* __restrict__ A, const u16* __restrict__ Bm,
    u16* __restrict__ Cb, float* __restrict__ Cf, int N,
    const float* __restrict__ bias0, const float* __restrict__ bias1) {
  __shared__ u16 As[128 * 32];  // 8 KB, unpadded (global_load_lds layout)
  __shared__ u16 Bs[128 * 32];
  const int tid = threadIdx.x;
  const int m0 = blockIdx.x * 128;
  const int n0 = blockIdx.y * 128;
  const int wave = tid >> 6, lane = tid & 63;
  const int wm = (wave >> 1) * 64, wn = (wave & 1) * 64;
  const int qm = lane & 15, quad = lane >> 4;
  f32x4 acc[4][4] = {};
  const int c0 = tid, c1 = tid + 256;  // 512 chunks of 16 B per 8 KB tile
  const size_t ga0 = (size_t)(m0 + (c0 >> 2)) * 256 + (c0 & 3) * 8;
  const size_t ga1 = (size_t)(m0 + (c1 >> 2)) * 256 + (c1 & 3) * 8;
  const size_t gb0 = (size_t)(n0 + (c0 >> 2)) * 256 + (c0 & 3) * 8;
  const size_t gb1 = (size_t)(n0 + (c1 >> 2)) * 256 + (c1 & 3) * 8;

  for (int k0 = 0; k0 < 256; k0 += 32) {
    __syncthreads();  // prev-iter LDS reads done
    async_cp16(A + ga0 + k0, As + c0 * 8);
    async_cp16(A + ga1 + k0, As + c1 * 8);
    async_cp16(Bm + gb0 + k0, Bs + c0 * 8);
    async_cp16(Bm + gb1 + k0, Bs + c1 * 8);
    __syncthreads();  // vmcnt drained -> LDS valid
    s16x8 af[4], bfr[4];
#pragma unroll
    for (int i = 0; i < 4; ++i)
      af[i] = *(const s16x8*)&As[(wm + i * 16 + qm) * 32 + quad * 8];
#pragma unroll
    for (int j = 0; j < 4; ++j)
      bfr[j] = *(const s16x8*)&Bs[(wn + j * 16 + qm) * 32 + quad * 8];
#pragma unroll
    for (int i = 0; i < 4; ++i)
#pragma unroll
      for (int j = 0; j < 4; ++j)
        acc[i][j] = __builtin_amdgcn_mfma_f32_16x16x32_bf16(af[i], bfr[j], acc[i][j], 0, 0, 0);
  }
#pragma unroll
  for (int i = 0; i < 4; ++i) {
    int rg = m0 + wm + i * 16 + quad * 4;  // C/D: row = quad*4+reg, col = lane&15
#pragma unroll
    for (int j = 0; j < 4; ++j) {
      int cg = n0 + wn + j * 16 + qm;
      float bias = 0.f;
      if (OF32) bias = bias0[cg] + bias1[cg];
#pragma unroll
      for (int r = 0; r < 4; ++r) {
        float v = acc[i][j][r] + bias;
        size_t idx = (size_t)(rg + r) * (size_t)N + cg;
        if (OF32) Cf[idx] = v; else Cb[idx] = f2bf(v);
      }
    }
  }
}

// Persistent-chunk scan: 64 blocks = 16 batches x 4 o-slices of 64.
// 512 thr: cluster of 8 lanes per output o (8-way K-split, 32 k each).
// U slice in REGISTERS (packed bf16x2, 64 VGPRs). h handoff: producer
// publishes 32 packed dwords + release tag (monotonic); consumers poll only
// their one producer's tag, data slots double-buffered by step parity.
// Own-block slice short-circuits via LDS. Tags/hdata persist across chunks.
__global__ __launch_bounds__(512, 2) void scan_kernel(
    const u16* __restrict__ Y, const float* __restrict__ wx,
    const u16* __restrict__ Ubt, const float* __restrict__ Bb,
    float* cbuf, u32* tags, u32* hdata, float* __restrict__ out,
    int t0, int Tc) {
  __shared__ u32 hown[2][32];
  const int tid = threadIdx.x;
  const int b = blockIdx.x >> 2;
  const int p = blockIdx.x & 3;
  const int obase = p << 6;
  const int oo = tid >> 3;   // 0..63
  const int s = tid & 7;     // K octant: k in [32s, 32s+32)
  const int o = obase + oo;
  const int myp = s >> 1;    // producer block of my k-slice
  const int half = s & 1;    // 16-dword half within producer line

  // U fragments: 4 gates x 4 uint4 (each uint4 = 8 bf16 over k)
  uint4 Ur[4][4];
  const uint4* Ub4 = (const uint4*)Ubt;
#pragma unroll
  for (int g = 0; g < 4; ++g) {
    int row = (g << 8) + o;
#pragma unroll
    for (int j = 0; j < 4; ++j) Ur[g][j] = Ub4[(size_t)row * 32 + s * 4 + j];
  }

  float c = cbuf[(b << 8) + o];
  const float bbias = Bb[o];
  u32* mytag = tags + ((b << 2) + p) * 16;

  // init own-slice LDS mirror for parity t0&1 (prev chunk's h_t0, or zeros)
  if (tid < 32)
    hown[t0 & 1][tid] = hdata[((((b << 1) + (t0 & 1)) << 2) + p) * 32 + tid];

  const int tend = t0 + Tc;
  const u16* Yp = Y + (size_t)b * 65536 + (size_t)o * 256 + s * 32;
  uint4 Yc[4];
  {
    const uint4* y0 = (const uint4*)Yp;
    Yc[0] = y0[0]; Yc[1] = y0[1]; Yc[2] = y0[2]; Yc[3] = y0[3];
  }
  const float* wxp0 = wx + ((size_t)t0 * 16 + b) * 1024 + o;
  float w0 = wxp0[0], w1 = wxp0[256], w2 = wxp0[512], w3 = wxp0[768];
  float hn = 0.f;
  __syncthreads();

  for (int t = t0; t < tend; ++t) {
    // prefetch next step's x-dependent data (fills during the h wait)
    int dn = (t + 1 < tend) ? (t + 1 - t0) : (t - t0);
    const uint4* ynp = (const uint4*)(Yp + (size_t)dn * 1048576);
    uint4 yn0 = ynp[0], yn1 = ynp[1], yn2 = ynp[2], yn3 = ynp[3];
    int tn = (t + 1 < tend) ? (t + 1) : t;
    const float* nwp = wx + ((size_t)tn * 16 + b) * 1024 + o;
    float nw0 = nwp[0], nw1 = nwp[256], nw2 = nwp[512], nw3 = nwp[768];

    // acquire h_t slice (32 values, packed bf16x2)
    const int par = t & 1;
    u32 hd[16];
    if (myp == p) {
      const u32* hp = &hown[par][half << 4];
#pragma unroll
      for (int j = 0; j < 16; ++j) hd[j] = hp[j];
    } else {
      u32* tagp = tags + ((b << 2) + myp) * 16;
      while (__hip_atomic_load(tagp, __ATOMIC_ACQUIRE, __HIP_MEMORY_SCOPE_AGENT) < (u32)t) {}
      const u32* hp = hdata + ((((b << 1) + par) << 2) + myp) * 32 + (half << 4);
#pragma unroll
      for (int j = 0; j < 16; ++j) hd[j] = hp[j];  // plain loads post-acquire
    }

    float a0 = 0.f, a1 = 0.f, a2 = 0.f, a3 = 0.f, am = 0.f;
#pragma unroll
    for (int j = 0; j < 4; ++j) {
      u32 h0 = hd[4 * j], h1 = hd[4 * j + 1], h2 = hd[4 * j + 2], h3 = hd[4 * j + 3];
      a0 = dotp(Ur[0][j].x, h0, a0); a0 = dotp(Ur[0][j].y, h1, a0);
      a0 = dotp(Ur[0][j].z, h2, a0); a0 = dotp(Ur[0][j].w, h3, a0);
      a1 = dotp(Ur[1][j].x, h0, a1); a1 = dotp(Ur[1][j].y, h1, a1);
      a1 = dotp(Ur[1][j].z, h2, a1); a1 = dotp(Ur[1][j].w, h3, a1);
      a2 = dotp(Ur[2][j].x, h0, a2); a2 = dotp(Ur[2][j].y, h1, a2);
      a2 = dotp(Ur[2][j].z, h2, a2); a2 = dotp(Ur[2][j].w, h3, a2);
      a3 = dotp(Ur[3][j].x, h0, a3); a3 = dotp(Ur[3][j].y, h1, a3);
      a3 = dotp(Ur[3][j].z, h2, a3); a3 = dotp(Ur[3][j].w, h3, a3);
      am = dotp(Yc[j].x, h0, am);   am = dotp(Yc[j].y, h1, am);
      am = dotp(Yc[j].z, h2, am);   am = dotp(Yc[j].w, h3, am);
    }
#pragma unroll
    for (int mk = 1; mk < 8; mk <<= 1) {
      a0 += __shfl_xor(a0, mk, 8);
      a1 += __shfl_xor(a1, mk, 8);
      a2 += __shfl_xor(a2, mk, 8);
      a3 += __shfl_xor(a3, mk, 8);
      am += __shfl_xor(am, mk, 8);
    }
    float gi = sigm_(a0 + w0);
    float gf = sigm_(a1 + w1);
    float go = sigm_(a2 + w2);
    float gg = tanh_(a3 + w3);
    float mm = tanh_(am + bbias);
    c = gf * c + gi * gg + 0.1f * mm;
    hn = go * tanh_(c);  // identical across the 8-lane cluster

    const int npar = (t + 1) & 1;
    float hnext = __shfl_down(hn, 8);  // oo+1 cluster's hn (same wave)
    if (s == 0) {
      out[((size_t)b * 512 + t) * 256 + o] = hn;
      if (!(oo & 1)) {
        u32 pk = (u32)f2bf(hn) | ((u32)f2bf(hnext) << 16);
        hown[npar][oo >> 1] = pk;
        __hip_atomic_store(hdata + ((((b << 1) + npar) << 2) + p) * 32 + (oo >> 1),
                           pk, __ATOMIC_RELAXED, __HIP_MEMORY_SCOPE_AGENT);
      }
    }
    Yc[0] = yn0; Yc[1] = yn1; Yc[2] = yn2; Yc[3] = yn3;
    w0 = nw0; w1 = nw1; w2 = nw2; w3 = nw3;
    __syncthreads();  // all waves' hdata stores drained (vmcnt before barrier)
    if (tid == 0)
      __hip_atomic_store(mytag, (u32)(t + 1), __ATOMIC_RELEASE, __HIP_MEMORY_SCOPE_AGENT);
  }
  if (s == 0) {
    cbuf[(b << 8) + o] = c;
    out[(size_t)BTH + (b << 8) + o] = hn;          // final h
    out[(size_t)BTH + 4096 + (b << 8) + o] = c;    // final c
  }
}

extern "C" void kernel_launch(void* const* d_in, const int* in_sizes, int n_in,
                              void* d_out, int out_size, void* d_ws, size_t ws_size,
                              hipStream_t stream) {
  const float* x  = (const float*)d_in[0];
  const float* Ww = (const float*)d_in[1];
  const float* Wb = (const float*)d_in[2];
  const float* Uw = (const float*)d_in[3];
  const float* Ub = (const float*)d_in[4];
  const float* Bw = (const float*)d_in[5];
  const float* Bb = (const float*)d_in[6];
  float* out = (float*)d_out;

  char* ws = (char*)d_ws;
  const size_t WX_B  = (size_t)512 * 16 * 1024 * 4;  // 33.5 MB
  const size_t XB_B  = (size_t)8192 * 256 * 2;       // 4.2 MB
  const size_t BTT_B = (size_t)65536 * 256 * 2;      // 33.5 MB
  const size_t WBT_B = (size_t)1024 * 256 * 2;       // 0.5 MB
  const size_t UBT_B = (size_t)1024 * 256 * 2;       // 0.5 MB
  const size_t CB_B  = 16384;                        // cbuf 16*256 f32
  const size_t TG_B  = 4096;                         // tags 16*4*16 u32
  const size_t HD_B  = 16384;                        // hdata 16*2*4*32 u32
  const size_t ST_B  = CB_B + TG_B + HD_B;
  const size_t fixedB = WX_B + XB_B + BTT_B + WBT_B + UBT_B + ST_B;
  size_t avail = (ws_size > fixedB) ? (ws_size - fixedB) : 0;
  long Tc = (long)(avail / 2097152);  // Y bytes per timestep (bf16)
  if (Tc > 512) Tc = 512;
  Tc &= ~7L;
  if (Tc < 8) Tc = 8;

  u16* Y      = (u16*)ws;
  size_t YB   = (size_t)Tc * 2097152;
  float* wx   = (float*)(ws + YB);
  u16* xb     = (u16*)(ws + YB + WX_B);
  u16* Btt    = (u16*)(ws + YB + WX_B + XB_B);
  u16* Wbt    = (u16*)(ws + YB + WX_B + XB_B + BTT_B);
  u16* Ubt    = (u16*)(ws + YB + WX_B + XB_B + BTT_B + WBT_B);
  char* st    = ws + YB + WX_B + XB_B + BTT_B + WBT_B + UBT_B;
  float* cbuf = (float*)st;
  u32* tags   = (u32*)(st + CB_B);
  u32* hdata  = (u32*)(st + CB_B + TG_B);

  hipMemsetAsync(st, 0, ST_B, stream);  // c0=0, tags=0, h_0=0
  cast_x_kernel<<<8192, 256, 0, stream>>>(x, xb);
  cast_w_kernel<<<1024, 256, 0, stream>>>(Ww, Wbt, 262144);
  cast_w_kernel<<<1024, 256, 0, stream>>>(Uw, Ubt, 262144);
  transpose_b_kernel<<<dim3(16, 256), 256, 0, stream>>>(Bw, Btt);
  gemm_nt<true><<<dim3(64, 8), 256, 0, stream>>>(xb, Wbt, nullptr, wx, 1024, Wb, Ub);

  for (int t0 = 0; t0 < 512; t0 += (int)Tc) {
    int Tcur = (512 - t0 < (int)Tc) ? (512 - t0) : (int)Tc;
    gemm_nt<false><<<dim3(Tcur * 16 / 128, 512), 256, 0, stream>>>(
        xb + (size_t)t0 * 4096, Btt, Y, nullptr, 65536, nullptr, nullptr);
    scan_kernel<<<64, 512, 0, stream>>>(Y, wx, Ubt, Bb, cbuf, tags, hdata, out, t0, Tcur);
  }
}

// Round 3
// 2182.982 us; speedup vs baseline: 2.4418x; 2.4418x over previous
//
#include <hip/hip_runtime.h>

typedef unsigned short u16;
typedef unsigned int u32;
typedef short s16x8 __attribute__((ext_vector_type(8)));
typedef float f32x4 __attribute__((ext_vector_type(4)));
typedef __bf16 bf16x2 __attribute__((ext_vector_type(2)));

#define BTH 2097152  // 16*512*256

__device__ __forceinline__ u16 f2bf(float f) {
  u32 u = __float_as_uint(f);
  u32 r = (u + 0x7FFFu + ((u >> 16) & 1u)) >> 16;  // RNE
  return (u16)r;
}
__device__ __forceinline__ float bf2f(u16 u) {
  return __uint_as_float(((u32)u) << 16);
}
__device__ __forceinline__ float sigm_(float x) { return 1.f / (1.f + __expf(-x)); }
__device__ __forceinline__ float tanh_(float x) {
  x = fminf(15.f, fmaxf(-15.f, x));
  float e = __expf(2.f * x);
  return (e - 1.f) / (e + 1.f);
}

#if defined(__has_builtin)
#if __has_builtin(__builtin_amdgcn_fdot2_f32_bf16)
#define HAVE_BF16_DOT2 1
#endif
#endif

// acc += dot(bf16x2(a), bf16x2(b))
__device__ __forceinline__ float dotp(u32 a, u32 b, float acc) {
#ifdef HAVE_BF16_DOT2
  return __builtin_amdgcn_fdot2_f32_bf16(__builtin_bit_cast(bf16x2, a),
                                         __builtin_bit_cast(bf16x2, b), acc, false);
#else
  acc += bf2f((u16)(a & 0xFFFFu)) * bf2f((u16)(b & 0xFFFFu));
  acc += bf2f((u16)(a >> 16)) * bf2f((u16)(b >> 16));
  return acc;
#endif
}

__device__ __forceinline__ void async_cp16(const u16* g, u16* l) {
  __builtin_amdgcn_global_load_lds(
      (const __attribute__((address_space(1))) void*)g,
      (__attribute__((address_space(3))) void*)l, 16, 0, 0);
}

// x [b][t][d] f32 -> xb [(t*16+b)][d] bf16
__global__ void cast_x_kernel(const float* __restrict__ x, u16* __restrict__ xb) {
  int e = blockIdx.x * 256 + threadIdx.x;  // < 2097152
  int d = e & 255;
  int r = e >> 8;  // b*512 + t
  int bb = r >> 9, t = r & 511;
  xb[(size_t)((t << 4) | bb) * 256 + d] = f2bf(x[e]);
}

__global__ void cast_w_kernel(const float* __restrict__ w, u16* __restrict__ o, int n) {
  int e = blockIdx.x * 256 + threadIdx.x;
  if (e < n) o[e] = f2bf(w[e]);
}

// B_w [o][d][h] f32 -> Btt [(o*256+h)][d] bf16  (n-major for GEMM B-operand)
__global__ void transpose_b_kernel(const float* __restrict__ Bw, u16* __restrict__ Btt) {
  __shared__ float T[64][65];
  const int o = blockIdx.y;
  const int d0 = (blockIdx.x >> 2) * 64;
  const int h0 = (blockIdx.x & 3) * 64;
  const int tid = threadIdx.x;
  const float* src = Bw + (size_t)o * 65536;
#pragma unroll
  for (int k = 0; k < 16; ++k) {
    int idx = tid + k * 256;
    int rr = idx >> 6, cc = idx & 63;
    T[rr][cc] = src[(size_t)(d0 + rr) * 256 + h0 + cc];
  }
  __syncthreads();
#pragma unroll
  for (int k = 0; k < 16; ++k) {
    int idx = tid + k * 256;
    int rr = idx >> 6, cc = idx & 63;
    Btt[(size_t)(o * 256 + h0 + rr) * 256 + d0 + cc] = f2bf(T[cc][rr]);
  }
}

// C[m][n] = A[m][:] . Bm[n][:]   (A,Bm bf16 row-major over K=256; fp32 accum)
template <bool OF32>
__global__ __launch_bounds__(256) void gemm_nt(
    const u16* __restrict__ A, const u16* __restrict__ Bm,
    u16* __restrict__ Cb, float* __restrict__ Cf, int N,
    const float* __restrict__ bias0, const float* __restrict__ bias1) {
  __shared__ u16 As[128 * 32];  // 8 KB, unpadded (global_load_lds layout)
  __shared__ u16 Bs[128 * 32];
  const int tid = threadIdx.x;
  const int m0 = blockIdx.x * 128;
  const int n0 = blockIdx.y * 128;
  const int wave = tid >> 6, lane = tid & 63;
  const int wm = (wave >> 1) * 64, wn = (wave & 1) * 64;
  const int qm = lane & 15, quad = lane >> 4;
  f32x4 acc[4][4] = {};
  const int c0 = tid, c1 = tid + 256;  // 512 chunks of 16 B per 8 KB tile
  const size_t ga0 = (size_t)(m0 + (c0 >> 2)) * 256 + (c0 & 3) * 8;
  const size_t ga1 = (size_t)(m0 + (c1 >> 2)) * 256 + (c1 & 3) * 8;
  const size_t gb0 = (size_t)(n0 + (c0 >> 2)) * 256 + (c0 & 3) * 8;
  const size_t gb1 = (size_t)(n0 + (c1 >> 2)) * 256 + (c1 & 3) * 8;

  for (int k0 = 0; k0 < 256; k0 += 32) {
    __syncthreads();  // prev-iter LDS reads done
    async_cp16(A + ga0 + k0, As + c0 * 8);
    async_cp16(A + ga1 + k0, As + c1 * 8);
    async_cp16(Bm + gb0 + k0, Bs + c0 * 8);
    async_cp16(Bm + gb1 + k0, Bs + c1 * 8);
    __syncthreads();  // vmcnt drained -> LDS valid
    s16x8 af[4], bfr[4];
#pragma unroll
    for (int i = 0; i < 4; ++i)
      af[i] = *(const s16x8*)&As[(wm + i * 16 + qm) * 32 + quad * 8];
#pragma unroll
    for (int j = 0; j < 4; ++j)
      bfr[j] = *(const s16x8*)&Bs[(wn + j * 16 + qm) * 32 + quad * 8];
#pragma unroll
    for (int i = 0; i < 4; ++i)
#pragma unroll
      for (int j = 0; j < 4; ++j)
        acc[i][j] = __builtin_amdgcn_mfma_f32_16x16x32_bf16(af[i], bfr[j], acc[i][j], 0, 0, 0);
  }
#pragma unroll
  for (int i = 0; i < 4; ++i) {
    int rg = m0 + wm + i * 16 + quad * 4;  // C/D: row = quad*4+reg, col = lane&15
#pragma unroll
    for (int j = 0; j < 4; ++j) {
      int cg = n0 + wn + j * 16 + qm;
      float bias = 0.f;
      if (OF32) bias = bias0[cg] + bias1[cg];
#pragma unroll
      for (int r = 0; r < 4; ++r) {
        float v = acc[i][j][r] + bias;
        size_t idx = (size_t)(rg + r) * (size_t)N + cg;
        if (OF32) Cf[idx] = v; else Cb[idx] = f2bf(v);
      }
    }
  }
}

// Persistent-chunk scan: 64 blocks = 16 batches x 4 o-slices of 64.
// ALL cross-block traffic is RELAXED agent atomics (sc0/sc1 cache-bypass, NO
// acquire/release -> no buffer_inv/wb L2 maintenance). Ordering guarantee:
// producer h-stores drain (vmcnt(0) inside __syncthreads) BEFORE the tag
// store issues; consumer reads data only after observing tag (compiler
// barrier pins load order; relaxed-atomic loads bypass stale L1/L2).
__global__ __launch_bounds__(512, 2) void scan_kernel(
    const u16* __restrict__ Y, const float* __restrict__ wx,
    const u16* __restrict__ Ubt, const float* __restrict__ Bb,
    float* cbuf, u32* tags, u32* hdata, float* __restrict__ out,
    int t0, int Tc) {
  __shared__ u32 hown[2][32];
  const int tid = threadIdx.x;
  const int b = blockIdx.x >> 2;
  const int p = blockIdx.x & 3;
  const int obase = p << 6;
  const int oo = tid >> 3;   // 0..63
  const int s = tid & 7;     // K octant: k in [32s, 32s+32)
  const int o = obase + oo;
  const int myp = s >> 1;    // producer block of my k-slice
  const int half = s & 1;    // 16-dword half within producer line

  // U fragments: 4 gates x 4 uint4 (each uint4 = 8 bf16 over k)
  uint4 Ur[4][4];
  const uint4* Ub4 = (const uint4*)Ubt;
#pragma unroll
  for (int g = 0; g < 4; ++g) {
    int row = (g << 8) + o;
#pragma unroll
    for (int j = 0; j < 4; ++j) Ur[g][j] = Ub4[(size_t)row * 32 + s * 4 + j];
  }

  float c = cbuf[(b << 8) + o];
  const float bbias = Bb[o];
  u32* mytag = tags + ((b << 2) + p) * 16;

  // init own-slice LDS mirror for parity t0&1 (prev chunk's h_t0, or zeros)
  if (tid < 32)
    hown[t0 & 1][tid] = hdata[((((b << 1) + (t0 & 1)) << 2) + p) * 32 + tid];

  const int tend = t0 + Tc;
  const u16* Yp = Y + (size_t)b * 65536 + (size_t)o * 256 + s * 32;
  uint4 Yc[4];
  {
    const uint4* y0 = (const uint4*)Yp;
    Yc[0] = y0[0]; Yc[1] = y0[1]; Yc[2] = y0[2]; Yc[3] = y0[3];
  }
  const float* wxp0 = wx + ((size_t)t0 * 16 + b) * 1024 + o;
  float w0 = wxp0[0], w1 = wxp0[256], w2 = wxp0[512], w3 = wxp0[768];
  float hn = 0.f;
  __syncthreads();

  for (int t = t0; t < tend; ++t) {
    // prefetch next step's x-dependent data (fills during the h wait)
    int dn = (t + 1 < tend) ? (t + 1 - t0) : (t - t0);
    const uint4* ynp = (const uint4*)(Yp + (size_t)dn * 1048576);
    uint4 yn0 = ynp[0], yn1 = ynp[1], yn2 = ynp[2], yn3 = ynp[3];
    int tn = (t + 1 < tend) ? (t + 1) : t;
    const float* nwp = wx + ((size_t)tn * 16 + b) * 1024 + o;
    float nw0 = nwp[0], nw1 = nwp[256], nw2 = nwp[512], nw3 = nwp[768];

    // acquire h_t slice (32 values, packed bf16x2) -- RELAXED poll, no
    // cache-maintenance; ordering via issue order + compiler barrier.
    const int par = t & 1;
    u32 hd[16];
    if (myp == p) {
      const u32* hp = &hown[par][half << 4];
#pragma unroll
      for (int j = 0; j < 16; ++j) hd[j] = hp[j];
    } else {
      u32* tagp = tags + ((b << 2) + myp) * 16;
      while (__hip_atomic_load(tagp, __ATOMIC_RELAXED, __HIP_MEMORY_SCOPE_AGENT) < (u32)t) {}
      __asm__ volatile("" ::: "memory");  // pin data loads after poll exit
      const u32* hp = hdata + ((((b << 1) + par) << 2) + myp) * 32 + (half << 4);
#pragma unroll
      for (int j = 0; j < 16; ++j)
        hd[j] = __hip_atomic_load(hp + j, __ATOMIC_RELAXED, __HIP_MEMORY_SCOPE_AGENT);
    }

    float a0 = 0.f, a1 = 0.f, a2 = 0.f, a3 = 0.f, am = 0.f;
#pragma unroll
    for (int j = 0; j < 4; ++j) {
      u32 h0 = hd[4 * j], h1 = hd[4 * j + 1], h2 = hd[4 * j + 2], h3 = hd[4 * j + 3];
      a0 = dotp(Ur[0][j].x, h0, a0); a0 = dotp(Ur[0][j].y, h1, a0);
      a0 = dotp(Ur[0][j].z, h2, a0); a0 = dotp(Ur[0][j].w, h3, a0);
      a1 = dotp(Ur[1][j].x, h0, a1); a1 = dotp(Ur[1][j].y, h1, a1);
      a1 = dotp(Ur[1][j].z, h2, a1); a1 = dotp(Ur[1][j].w, h3, a1);
      a2 = dotp(Ur[2][j].x, h0, a2); a2 = dotp(Ur[2][j].y, h1, a2);
      a2 = dotp(Ur[2][j].z, h2, a2); a2 = dotp(Ur[2][j].w, h3, a2);
      a3 = dotp(Ur[3][j].x, h0, a3); a3 = dotp(Ur[3][j].y, h1, a3);
      a3 = dotp(Ur[3][j].z, h2, a3); a3 = dotp(Ur[3][j].w, h3, a3);
      am = dotp(Yc[j].x, h0, am);   am = dotp(Yc[j].y, h1, am);
      am = dotp(Yc[j].z, h2, am);   am = dotp(Yc[j].w, h3, am);
    }
#pragma unroll
    for (int mk = 1; mk < 8; mk <<= 1) {
      a0 += __shfl_xor(a0, mk, 8);
      a1 += __shfl_xor(a1, mk, 8);
      a2 += __shfl_xor(a2, mk, 8);
      a3 += __shfl_xor(a3, mk, 8);
      am += __shfl_xor(am, mk, 8);
    }
    float gi = sigm_(a0 + w0);
    float gf = sigm_(a1 + w1);
    float go = sigm_(a2 + w2);
    float gg = tanh_(a3 + w3);
    float mm = tanh_(am + bbias);
    c = gf * c + gi * gg + 0.1f * mm;
    hn = go * tanh_(c);  // identical across the 8-lane cluster

    const int npar = (t + 1) & 1;
    float hnext = __shfl_down(hn, 8);  // oo+1 cluster's hn (same wave)
    if (s == 0) {
      out[((size_t)b * 512 + t) * 256 + o] = hn;
      if (!(oo & 1)) {
        u32 pk = (u32)f2bf(hn) | ((u32)f2bf(hnext) << 16);
        hown[npar][oo >> 1] = pk;
        __hip_atomic_store(hdata + ((((b << 1) + npar) << 2) + p) * 32 + (oo >> 1),
                           pk, __ATOMIC_RELAXED, __HIP_MEMORY_SCOPE_AGENT);
      }
    }
    Yc[0] = yn0; Yc[1] = yn1; Yc[2] = yn2; Yc[3] = yn3;
    w0 = nw0; w1 = nw1; w2 = nw2; w3 = nw3;
    __syncthreads();  // drains vmcnt(0): all h stores at coherence point
    if (tid == 0)
      __hip_atomic_store(mytag, (u32)(t + 1), __ATOMIC_RELAXED, __HIP_MEMORY_SCOPE_AGENT);
  }
  if (s == 0) {
    cbuf[(b << 8) + o] = c;
    out[(size_t)BTH + (b << 8) + o] = hn;          // final h
    out[(size_t)BTH + 4096 + (b << 8) + o] = c;    // final c
  }
}

extern "C" void kernel_launch(void* const* d_in, const int* in_sizes, int n_in,
                              void* d_out, int out_size, void* d_ws, size_t ws_size,
                              hipStream_t stream) {
  const float* x  = (const float*)d_in[0];
  const float* Ww = (const float*)d_in[1];
  const float* Wb = (const float*)d_in[2];
  const float* Uw = (const float*)d_in[3];
  const float* Ub = (const float*)d_in[4];
  const float* Bw = (const float*)d_in[5];
  const float* Bb = (const float*)d_in[6];
  float* out = (float*)d_out;

  char* ws = (char*)d_ws;
  const size_t WX_B  = (size_t)512 * 16 * 1024 * 4;  // 33.5 MB
  const size_t XB_B  = (size_t)8192 * 256 * 2;       // 4.2 MB
  const size_t BTT_B = (size_t)65536 * 256 * 2;      // 33.5 MB
  const size_t WBT_B = (size_t)1024 * 256 * 2;       // 0.5 MB
  const size_t UBT_B = (size_t)1024 * 256 * 2;       // 0.5 MB
  const size_t CB_B  = 16384;                        // cbuf 16*256 f32
  const size_t TG_B  = 4096;                         // tags 16*4*16 u32
  const size_t HD_B  = 16384;                        // hdata 16*2*4*32 u32
  const size_t ST_B  = CB_B + TG_B + HD_B;
  const size_t fixedB = WX_B + XB_B + BTT_B + WBT_B + UBT_B + ST_B;
  size_t avail = (ws_size > fixedB) ? (ws_size - fixedB) : 0;
  long Tc = (long)(avail / 2097152);  // Y bytes per timestep (bf16)
  if (Tc > 512) Tc = 512;
  Tc &= ~7L;
  if (Tc < 8) Tc = 8;

  u16* Y      = (u16*)ws;
  size_t YB   = (size_t)Tc * 2097152;
  float* wx   = (float*)(ws + YB);
  u16* xb     = (u16*)(ws + YB + WX_B);
  u16* Btt    = (u16*)(ws + YB + WX_B + XB_B);
  u16* Wbt    = (u16*)(ws + YB + WX_B + XB_B + BTT_B);
  u16* Ubt    = (u16*)(ws + YB + WX_B + XB_B + BTT_B + WBT_B);
  char* st    = ws + YB + WX_B + XB_B + BTT_B + WBT_B + UBT_B;
  float* cbuf = (float*)st;
  u32* tags   = (u32*)(st + CB_B);
  u32* hdata  = (u32*)(st + CB_B + TG_B);

  hipMemsetAsync(st, 0, ST_B, stream);  // c0=0, tags=0, h_0=0
  cast_x_kernel<<<8192, 256, 0, stream>>>(x, xb);
  cast_w_kernel<<<1024, 256, 0, stream>>>(Ww, Wbt, 262144);
  cast_w_kernel<<<1024, 256, 0, stream>>>(Uw, Ubt, 262144);
  transpose_b_kernel<<<dim3(16, 256), 256, 0, stream>>>(Bw, Btt);
  gemm_nt<true><<<dim3(64, 8), 256, 0, stream>>>(xb, Wbt, nullptr, wx, 1024, Wb, Ub);

  for (int t0 = 0; t0 < 512; t0 += (int)Tc) {
    int Tcur = (512 - t0 < (int)Tc) ? (512 - t0) : (int)Tc;
    gemm_nt<false><<<dim3(Tcur * 16 / 128, 512), 256, 0, stream>>>(
        xb + (size_t)t0 * 4096, Btt, Y, nullptr, 65536, nullptr, nullptr);
    scan_kernel<<<64, 512, 0, stream>>>(Y, wx, Ubt, Bb, cbuf, tags, hdata, out, t0, Tcur);
  }
}